// Round 6
// baseline (194.232 us; speedup 1.0000x reference)
//
#include <hip/hip_runtime.h>
#include <math.h>

#define BATCH 64
#define HIMG 224
#define WIMG 224
#define IMGPLANE (HIMG*WIMG)   // 50176
#define CF 512
#define HF 28
#define WF 28
#define POS (HF*WF)            // 784
#define ALPHA_C 0.15f
#define EPS_C 1e-6f

#define STRIPS 14              // 16-row strips per sample
#define SROWS 16
#define GROWS 20               // SROWS + 4 halo rows
#define GSTR 229               // LDS row stride for gray (odd)
#define VSTR 261               // LDS row stride for var (swizzled cols)
#define SHN 4580               // max(GROWS*GSTR=4580, SROWS*VSTR=4176)

#define NZ 16                  // channel groups
#define CPG 32                 // channels per group
#define NATTN 784              // 784 blocks x 256 thr = 200,704 = 64*16*196 quad-tasks
#define NVARH (STRIPS*BATCH)   // 896
// interleave: groups of 15 blocks = 7 attn + 8 varh (1680 = 112*15)

// ---- ws layout (in floats) ----
#define OFF_HRES 0
#define HRES_CNT (BATCH*HIMG*WF)             // 401,408
#define OFF_BMM  (OFF_HRES + HRES_CNT)       // 1,792: per-strip [min,max]
#define OFF_AP   (OFF_BMM + BATCH*STRIPS*2)  // 802,816: NZ partial channel sums
#define OFF_SAL  (OFF_AP + NZ*BATCH*POS)     // 50,176: normalized sal per sample
#define OFF_ATT  (OFF_SAL + BATCH*POS)       // 50,176: raw attn per sample
#define OFF_PMM  (OFF_ATT + BATCH*POS)       // 512: per-(sample,quarter) attn [min,max]
#define OFF_ACC  (OFF_PMM + BATCH*8)         // loss accumulator
#define OFF_CNT  (OFF_ACC + 1)               // done counter (uint slot)
#define OFF_QCNT (OFF_CNT + 1)               // 64 uints: per-sample quarter counters

typedef float f4v __attribute__((ext_vector_type(4)));

// Non-temporal 16B load: identical value, `nt` cache policy. Round-6 theory:
// fat_k's read rate is pinned at ~2.35 TB/s regardless of occupancy/MLP
// (rounds 0-5 all null) -> per-CU L1 fill-path rate cap on zero-reuse
// streams. nt relaxes L1 retention/fill for exactly this case.
__device__ __forceinline__ f4v nt4(const float* p) {
    return __builtin_nontemporal_load((const f4v*)p);
}

__global__ __launch_bounds__(256, 2) void fat_k(const float* __restrict__ img,
                                                const float* __restrict__ f,
                                                float* __restrict__ ws) {
    __shared__ float sh[SHN];   // gray, later overlaid with var (18,320 B)
    __shared__ float wred[8];
    int bid = blockIdx.x;
    int tid = threadIdx.x;
    int g15 = bid / 15, r15 = bid - 15 * g15;

    if (r15 < 7) {
        // -------- attn branch: flat task t = (b, z of 16, quad q) --------
        int at = g15 * 7 + r15;
        if (at == 0) {
            if (tid == 0) {
                ws[OFF_ACC] = 0.0f;
                ((unsigned*)ws)[OFF_CNT] = 0u;
            }
            if (tid < BATCH) ((unsigned*)ws)[OFF_QCNT + tid] = 0u;
        }
        int t = at * 256 + tid;                 // 0 .. 200703
        int b = t / (NZ * 196);
        int rem = t - b * (NZ * 196);
        int z = rem / 196, q = rem - z * 196;
        const float* fp = f + (size_t)(b * CF + z * CPG) * POS + 4 * q;
        float ax = 0.0f, ay = 0.0f, az = 0.0f, aw = 0.0f;
        // ascending channel order within group; groups added in ascending z
        // downstream => element-wise arithmetic identical to round-5.
        #pragma unroll
        for (int c = 0; c < CPG; c++) {
            f4v u = nt4(fp + (size_t)c * POS);
            ax += u.x * u.x; ay += u.y * u.y;
            az += u.z * u.z; aw += u.w * u.w;
        }
        float4 o = make_float4(ax, ay, az, aw);
        *(float4*)(ws + OFF_AP + (size_t)(z * BATCH + b) * POS + 4 * q) = o;
        return;
    }

    // -------- varh branch --------
    int vb = g15 * 8 + (r15 - 7);
    int b = vb / STRIPS, sy = vb - b * STRIPS;
    int y0 = sy * SROWS;
    const float* imb = img + (size_t)b * 3 * IMGPLANE;

    // stage gray interior via float4 (rows 16B-aligned: 224 floats/row)
    for (int i = tid; i < GROWS * 56; i += 256) {
        int gr = i / 56, q = i - gr * 56;
        int gy = y0 - 2 + gr;
        float gx0 = 0.0f, gx1 = 0.0f, gx2 = 0.0f, gx3 = 0.0f;
        if ((unsigned)gy < HIMG) {
            const float* row = imb + gy * WIMG + 4 * q;
            f4v a = nt4(row);
            f4v bb = nt4(row + IMGPLANE);
            f4v c = nt4(row + 2 * IMGPLANE);
            gx0 = 0.299f * a.x + 0.587f * bb.x + 0.114f * c.x;
            gx1 = 0.299f * a.y + 0.587f * bb.y + 0.114f * c.y;
            gx2 = 0.299f * a.z + 0.587f * bb.z + 0.114f * c.z;
            gx3 = 0.299f * a.w + 0.587f * bb.w + 0.114f * c.w;
        }
        int base = gr * GSTR + 2 + 4 * q;
        sh[base] = gx0; sh[base + 1] = gx1; sh[base + 2] = gx2; sh[base + 3] = gx3;
    }
    // zero gray col-halo (cols 0,1,226,227)
    if (tid < GROWS * 4) {
        int gr = tid >> 2, p = tid & 3;
        int gc = (p < 2) ? p : (224 + p);
        sh[gr * GSTR + gc] = 0.0f;
    }
    __syncthreads();

    // var into registers: thread (r = tid>>4, 14-col segment s = tid&15)
    int r = tid >> 4, s = tid & 15;
    int x0 = 14 * s;
    const float* gr0 = sh + r * GSTR;
    float c1[5], c2[5], vreg[14];
    #pragma unroll
    for (int m = 0; m < 5; m++) {
        float a = 0.0f, a2 = 0.0f;
        #pragma unroll
        for (int k = 0; k < 5; k++) {
            float u = gr0[k * GSTR + x0 + m];
            a += u; a2 += u * u;
        }
        c1[m] = a; c2[m] = a2;
    }
    float vmn = INFINITY, vmx = 0.0f;
    #pragma unroll
    for (int xi = 0; xi < 14; xi++) {
        int p = xi % 5;
        float s1 = c1[p], s2 = c2[p];
        #pragma unroll
        for (int m = 1; m < 5; m++) {
            s1 += c1[(p + m) % 5];
            s2 += c2[(p + m) % 5];
        }
        float m1 = s1 * 0.04f, m2 = s2 * 0.04f;
        float vv = fmaxf(m2 - m1 * m1, 0.0f);
        vreg[xi] = vv;
        vmn = fminf(vmn, vv); vmx = fmaxf(vmx, vv);
        if (xi < 13) {
            float a = 0.0f, a2 = 0.0f;
            #pragma unroll
            for (int k = 0; k < 5; k++) {
                float u = gr0[k * GSTR + x0 + xi + 5];
                a += u; a2 += u * u;
            }
            c1[p] = a; c2[p] = a2;
        }
    }
    #pragma unroll
    for (int o = 32; o > 0; o >>= 1) {
        vmn = fminf(vmn, __shfl_xor(vmn, o));
        vmx = fmaxf(vmx, __shfl_xor(vmx, o));
    }
    __syncthreads();   // all gray reads done -> safe to overlay with var
    int w = tid >> 6;
    if ((tid & 63) == 0) { wred[w] = vmn; wred[4 + w] = vmx; }
    // zero var col-halo (jh 0..3 and 228..231)
    if (tid < SROWS * 8) {
        int rr = tid >> 3, p = tid & 7;
        int jh = p + ((p < 4) ? 0 : 224);
        sh[rr * VSTR + jh + (jh >> 3)] = 0.0f;
    }
    // write var registers into overlaid buffer (swizzled cols)
    #pragma unroll
    for (int xi = 0; xi < 14; xi++) {
        int jh = x0 + xi + 4;
        sh[r * VSTR + jh + (jh >> 3)] = vreg[xi];
    }
    __syncthreads();   // var + wred ready
    if (tid == 0) {
        float mn = fminf(fminf(wred[0], wred[1]), fminf(wred[2], wred[3]));
        float mx = fmaxf(fmaxf(wred[4], wred[5]), fmaxf(wred[6], wred[7]));
        int blk = b * STRIPS + sy;
        ws[OFF_BMM + 2 * blk]     = mn;
        ws[OFF_BMM + 2 * blk + 1] = mx;
    }

    // horizontal 16-tap resize from LDS var; coalesced store of hres strip
    float* hb = ws + OFF_HRES + ((size_t)b * HIMG + y0) * WF;
    for (int idx = tid; idx < SROWS * WF; idx += 256) {   // 448
        int rr = idx / WF, i = idx - rr * WF;
        float acc = 0.0f, wsum = 0.0f;
        int j0 = 8 * i - 4;
        #pragma unroll
        for (int t = 0; t < 16; t++) {
            int j = j0 + t;
            float w_ = 8.0f - fabsf((float)t - 7.5f);
            int jh = j + 4;
            acc += w_ * sh[rr * VSTR + jh + (jh >> 3)];   // halo = 0 -> exact
            if ((unsigned)j < WIMG) wsum += w_;
        }
        hb[idx] = acc / wsum;
    }
}

// ---- fused_k, 4 blocks/sample (was 1): round-5 fused_k was a 64-block
// latency-bound tail (17 us for 4.8 MB). Phase A (per quarter): sal fully
// normalized (var minmax is already sample-global via BMM) + raw attn +
// quarter attn minmax. 4th-arriving block: final attn minmax + MSE. ----
__global__ __launch_bounds__(256) void fused_k(float* __restrict__ ws,
                                               float* __restrict__ out) {
    __shared__ float wred[8];
    __shared__ float s_vmn, s_vmx;
    __shared__ int s_last;
    int bid = blockIdx.x;
    int b = bid >> 2, qt = bid & 3;
    int tid = threadIdx.x;

    // var minmax from 14 strip pairs (first wave)
    if (tid < 64) {
        float mn = INFINITY, mx = 0.0f;
        if (tid < STRIPS) {
            mn = ws[OFF_BMM + 2 * (b * STRIPS + tid)];
            mx = ws[OFF_BMM + 2 * (b * STRIPS + tid) + 1];
        }
        #pragma unroll
        for (int o = 8; o > 0; o >>= 1) {
            mn = fminf(mn, __shfl_down(mn, o));
            mx = fmaxf(mx, __shfl_down(mx, o));
        }
        if (tid == 0) { s_vmn = mn; s_vmx = mx; }
    }
    __syncthreads();
    float vmn = s_vmn, vmx = s_vmx;
    float vden = vmx - vmn;
    bool vok = vden > EPS_C;

    // phase A: 196 positions of this quarter
    float amn = INFINITY, amx = -INFINITY;
    if (tid < 196) {
        int idx = qt * 196 + tid;
        int yo = idx / WF, x = idx - yo * WF;
        const float* hg = ws + OFF_HRES + (size_t)b * HIMG * WF;
        float acc = 0.0f, wsum = 0.0f;
        int j0 = 8 * yo - 4;
        #pragma unroll
        for (int t = 0; t < 16; t++) {
            int j = j0 + t;
            float w = 8.0f - fabsf((float)t - 7.5f);
            if ((unsigned)j < HIMG) { acc += w * hg[j * WF + x]; wsum += w; }
        }
        float sraw = acc / wsum;
        float salres = vok ? (sraw - vmn) / vden : 0.5f;
        const float* ap = ws + OFF_AP + (size_t)b * POS;
        float ssum = 0.0f;
        #pragma unroll
        for (int z = 0; z < NZ; z++)          // ascending z => c order 0..511
            ssum += ap[(size_t)z * BATCH * POS + idx];
        float a = sqrtf(ssum * (1.0f / CF));
        ws[OFF_SAL + b * POS + idx] = salres;
        ws[OFF_ATT + b * POS + idx] = a;
        amn = a; amx = a;
    }
    #pragma unroll
    for (int o = 32; o > 0; o >>= 1) {
        amn = fminf(amn, __shfl_xor(amn, o));
        amx = fmaxf(amx, __shfl_xor(amx, o));
    }
    int w = tid >> 6;
    if ((tid & 63) == 0) { wred[w] = amn; wred[4 + w] = amx; }
    __syncthreads();
    if (tid == 0) {
        float mn = fminf(fminf(wred[0], wred[1]), fminf(wred[2], wred[3]));
        float mx = fmaxf(fmaxf(wred[4], wred[5]), fmaxf(wred[6], wred[7]));
        ws[OFF_PMM + 8 * b + 2 * qt]     = mn;
        ws[OFF_PMM + 8 * b + 2 * qt + 1] = mx;
        __threadfence();                    // release sal/att/pmm
        unsigned old = atomicAdd((unsigned*)ws + OFF_QCNT + b, 1u);
        s_last = (old == 3u) ? 1 : 0;
    }
    __syncthreads();
    if (!s_last) return;
    __threadfence();                        // acquire all 4 quarters

    // phase B: final attn minmax + MSE for the whole sample
    float fmn = fminf(fminf(ws[OFF_PMM + 8 * b + 0], ws[OFF_PMM + 8 * b + 2]),
                      fminf(ws[OFF_PMM + 8 * b + 4], ws[OFF_PMM + 8 * b + 6]));
    float fmx = fmaxf(fmaxf(ws[OFF_PMM + 8 * b + 1], ws[OFF_PMM + 8 * b + 3]),
                      fmaxf(ws[OFF_PMM + 8 * b + 5], ws[OFF_PMM + 8 * b + 7]));
    float aden = fmx - fmn;
    bool aok = aden > EPS_C;
    float lsum = 0.0f;
    #pragma unroll
    for (int k = 0; k < 4; k++) {
        int idx = tid + 256 * k;
        if (idx < POS) {
            float an = aok ? (ws[OFF_ATT + b * POS + idx] - fmn) / aden : 0.5f;
            float d = an - ws[OFF_SAL + b * POS + idx];
            lsum += d * d;
        }
    }
    #pragma unroll
    for (int o = 32; o > 0; o >>= 1) lsum += __shfl_xor(lsum, o);
    if ((tid & 63) == 0) wred[w] = lsum;
    __syncthreads();
    if (tid == 0) {
        float part = wred[0] + wred[1] + wred[2] + wred[3];
        atomicAdd(ws + OFF_ACC, part);
        __threadfence();
        unsigned old = atomicAdd((unsigned*)ws + OFF_CNT, 1u);
        if (old == BATCH - 1) {
            float tot = atomicAdd(ws + OFF_ACC, 0.0f);  // device-coherent read
            out[0] = tot * (ALPHA_C / (float)(BATCH * POS));
        }
    }
}

extern "C" void kernel_launch(void* const* d_in, const int* in_sizes, int n_in,
                              void* d_out, int out_size, void* d_ws, size_t ws_size,
                              hipStream_t stream) {
    const float* features = (const float*)d_in[0];  // [64,512,28,28]
    const float* images   = (const float*)d_in[1];  // [64,3,224,224]
    float* ws  = (float*)d_ws;
    float* out = (float*)d_out;

    hipLaunchKernelGGL(fat_k,   dim3(NATTN + NVARH), dim3(256), 0, stream,
                       images, features, ws);
    hipLaunchKernelGGL(fused_k, dim3(4 * BATCH),     dim3(256), 0, stream, ws, out);
}